// Round 2
// baseline (1166.614 us; speedup 1.0000x reference)
//
#include <hip/hip_runtime.h>
#include <hip/hip_bf16.h>

#define T_STEPS 1000
#define BATCH   256
#define IN_C    32
#define HID     128
#define OUT_C   10

typedef __fp16 h2_t __attribute__((ext_vector_type(2)));

__device__ __forceinline__ float dot2f(uint32_t w, uint32_t a, float acc) {
#if __has_builtin(__builtin_amdgcn_fdot2)
  return __builtin_amdgcn_fdot2(__builtin_bit_cast(h2_t, a),
                                __builtin_bit_cast(h2_t, w), acc, false);
#else
  h2_t av = __builtin_bit_cast(h2_t, a);
  h2_t wv = __builtin_bit_cast(h2_t, w);
  return acc + (float)av[0] * (float)wv[0] + (float)av[1] * (float)wv[1];
#endif
}

__device__ __forceinline__ uint32_t pack_f16(float a, float b) {
#if __has_builtin(__builtin_amdgcn_cvt_pkrtz)
  auto p = __builtin_amdgcn_cvt_pkrtz(a, b);
  return __builtin_bit_cast(uint32_t, p);
#else
  h2_t p; p[0] = (__fp16)a; p[1] = (__fp16)b;
  return __builtin_bit_cast(uint32_t, p);
#endif
}

__device__ __forceinline__ float fast_tanh(float x) {
  float a = x * 2.88539008178f;                 // 2*log2(e)*x
  a = fminf(fmaxf(a, -126.f), 126.f);
#if __has_builtin(__builtin_amdgcn_exp2f)
  float t = __builtin_amdgcn_exp2f(a);
#else
  float t = exp2f(a);
#endif
#if __has_builtin(__builtin_amdgcn_rcpf)
  float r = __builtin_amdgcn_rcpf(t + 1.f);
#else
  float r = 1.f / (t + 1.f);
#endif
  return (t - 1.f) * r;
}

// ---------------- kernel 0: dt = max(min(diff(times)), 0.001) ----------------
__global__ __launch_bounds__(256) void k_dt(const float* __restrict__ times,
                                            float* __restrict__ dtb) {
  __shared__ float smin[256];
  int tid = threadIdx.x;
  float m = 1e30f;
  for (int t = tid; t < T_STEPS - 1; t += 256)
    m = fminf(m, times[t + 1] - times[t]);
  smin[tid] = m;
  __syncthreads();
  for (int off = 128; off > 0; off >>= 1) {
    if (tid < off) smin[tid] = fminf(smin[tid], smin[tid + off]);
    __syncthreads();
  }
  if (tid == 0) {
    float dt = fmaxf(smin[0], 0.001f);
    dtb[0] = dt;
    dtb[1] = sqrtf(dt);
  }
}

// ---------------- kernel 1: Euler-Maruyama SDE per trajectory ----------------
// block b = trajectory; 256 threads: j = tid>>1 (hidden unit), s = tid&1 (f vs g MLP)
__global__ __launch_bounds__(256) void k_sde(
    const float* __restrict__ x0, const float* __restrict__ dW,
    const int* __restrict__ fidx,
    const float* __restrict__ Winit, const float* __restrict__ binit,
    const float* __restrict__ Wf1, const float* __restrict__ bf1,
    const float* __restrict__ Wf2, const float* __restrict__ bf2,
    const float* __restrict__ Wg1, const float* __restrict__ bg1,
    const float* __restrict__ Wg2, const float* __restrict__ bg2,
    const float* __restrict__ dtb, float* __restrict__ zf) {
  const int b = blockIdx.x;
  const int tid = threadIdx.x;
  const int j = tid >> 1;
  const int s = tid & 1;

  __shared__ alignas(16) uint32_t zp[64];   // z as 64 f16-pairs
  __shared__ alignas(16) uint32_t hfp[64];  // tanh f-hidden
  __shared__ alignas(16) uint32_t hgp[64];  // tanh g-hidden

  const float dt  = dtb[0];
  const float sdt = dtb[1];

  // weight-stationary: pack this thread's columns of (layer1, layer2) as f16 pairs
  const float* M1 = s ? Wg1 : Wf1;
  const float* M2 = s ? Wg2 : Wf2;
  uint32_t wA[64], wB[64];
#pragma unroll
  for (int k = 0; k < 64; ++k) {
    wA[k] = pack_f16(M1[(2 * k) * HID + j], M1[(2 * k + 1) * HID + j]);
    wB[k] = pack_f16(M2[(2 * k) * HID + j], M2[(2 * k + 1) * HID + j]);
  }
  const float bias1 = (s ? bg1 : bf1)[j];
  const float bias2 = (s ? bg2 : bf2)[j];

  // z0 = x0 @ Winit + binit  (both s-lanes redundantly)
  float z = binit[j];
#pragma unroll
  for (int i = 0; i < IN_C; ++i)
    z = fmaf(x0[b * IN_C + i], Winit[i * HID + j], z);

  __fp16* zh = (__fp16*)zp;
  zh[j] = (__fp16)z;

  const int nsteps = fidx[b];  // in [0, T-1]

  const float* dwp = dW + (size_t)b * HID + j;
  const size_t sBH = (size_t)BATCH * HID;
  float dwA = dwp[0];
  float dwB = dwp[sBH];

  const uint4* zp4 = (const uint4*)zp;
  const uint4* hp4 = (const uint4*)(s ? hgp : hfp);
  __fp16* hdst     = (__fp16*)(s ? hgp : hfp);

  __syncthreads();

  for (int t = 0; t < nsteps; ++t) {
    float dwv = dwA;
    dwA = dwB;
    int tn = t + 2;
    if (tn > T_STEPS - 2) tn = T_STEPS - 2;
    dwB = dwp[(size_t)tn * sBH];  // prefetch ~2 steps ahead

    // layer 1: acc = z . W*1[:,j]   (4 partial chains for ILP)
    float a0 = bias1, a1 = 0.f, a2 = 0.f, a3 = 0.f;
#pragma unroll
    for (int c = 0; c < 16; ++c) {
      uint4 v = zp4[c];
      a0 = dot2f(wA[4 * c + 0], v.x, a0);
      a1 = dot2f(wA[4 * c + 1], v.y, a1);
      a2 = dot2f(wA[4 * c + 2], v.z, a2);
      a3 = dot2f(wA[4 * c + 3], v.w, a3);
    }
    float h1 = fast_tanh((a0 + a1) + (a2 + a3));
    hdst[j] = (__fp16)h1;
    __syncthreads();

    // layer 2: acc = h . W*2[:,j]
    float c0 = bias2, c1 = 0.f, c2 = 0.f, c3 = 0.f;
#pragma unroll
    for (int c = 0; c < 16; ++c) {
      uint4 v = hp4[c];
      c0 = dot2f(wB[4 * c + 0], v.x, c0);
      c1 = dot2f(wB[4 * c + 1], v.y, c1);
      c2 = dot2f(wB[4 * c + 2], v.z, c2);
      c3 = dot2f(wB[4 * c + 3], v.w, c3);
    }
    float acc = (c0 + c1) + (c2 + c3);
    float tg  = fast_tanh(acc);        // only meaningful for s=1 (g is tanh-bounded)
    float val = s ? tg : acc;
    float oth = __shfl_xor(val, 1, 64);
    float fv = s ? oth : val;
    float gv = s ? val : oth;
    z = fmaf(fv, dt, fmaf(gv, sdt * dwv, z));
    zh[j] = (__fp16)z;
    __syncthreads();
  }

  if (s == 0) zf[b * HID + j] = z;
}

// ---------------- kernel 2a: h = zf @ W1 + b1, per-block column partial stats --
__global__ __launch_bounds__(256) void k_ro1(const float* __restrict__ zf,
                                             const float* __restrict__ W1,
                                             const float* __restrict__ b1,
                                             float* __restrict__ hbuf,
                                             float* __restrict__ p1,
                                             float* __restrict__ p2) {
  int blk = blockIdx.x;  // 32 blocks x 8 rows
  int tid = threadIdx.x;
  int j = tid & 127, half = tid >> 7;
  int b0 = blk * 8 + half * 4;
  float acc[4];
  float bj = b1[j];
#pragma unroll
  for (int r = 0; r < 4; ++r) acc[r] = bj;
  for (int i = 0; i < HID; ++i) {
    float w = W1[i * HID + j];
#pragma unroll
    for (int r = 0; r < 4; ++r)
      acc[r] = fmaf(zf[(b0 + r) * HID + i], w, acc[r]);
  }
  float s1 = 0.f, s2 = 0.f;
#pragma unroll
  for (int r = 0; r < 4; ++r) {
    hbuf[(b0 + r) * HID + j] = acc[r];
    s1 += acc[r];
    s2 = fmaf(acc[r], acc[r], s2);
  }
  __shared__ float q1[2][128], q2[2][128];
  q1[half][j] = s1;
  q2[half][j] = s2;
  __syncthreads();
  if (tid < 128) {
    p1[blk * HID + tid] = q1[0][tid] + q1[1][tid];
    p2[blk * HID + tid] = q2[0][tid] + q2[1][tid];
  }
}

// ---------------- kernel 2b: BN + ReLU + W2 readout ---------------------------
__global__ __launch_bounds__(1024) void k_ro2(
    const float* __restrict__ hbuf, const float* __restrict__ p1,
    const float* __restrict__ p2, const float* __restrict__ gamma,
    const float* __restrict__ beta, const float* __restrict__ W2,
    const float* __restrict__ b2, float* __restrict__ out) {
  __shared__ float sa[128], sc[128];
  int tid = threadIdx.x;
  if (tid < 128) {
    float m = 0.f, q = 0.f;
    for (int blk = 0; blk < 32; ++blk) {
      m += p1[blk * HID + tid];
      q += p2[blk * HID + tid];
    }
    m *= (1.f / BATCH);
    q *= (1.f / BATCH);
    float var = q - m * m;
    float r = rsqrtf(var + 1e-5f);
    float a = gamma[tid] * r;
    sa[tid] = a;
    sc[tid] = beta[tid] - m * a;
  }
  __syncthreads();
  for (int idx = tid; idx < BATCH * OUT_C; idx += 1024) {
    int b = idx / OUT_C;
    int o = idx - b * OUT_C;
    float acc = b2[o];
    for (int jj = 0; jj < HID; ++jj) {
      float hn = fmaxf(fmaf(sa[jj], hbuf[b * HID + jj], sc[jj]), 0.f);
      acc = fmaf(hn, W2[jj * OUT_C + o], acc);
    }
    out[idx] = acc;
  }
}

extern "C" void kernel_launch(void* const* d_in, const int* in_sizes, int n_in,
                              void* d_out, int out_size, void* d_ws, size_t ws_size,
                              hipStream_t stream) {
  const float* times = (const float*)d_in[0];
  const float* x0    = (const float*)d_in[1];
  const float* dW    = (const float*)d_in[2];
  const int*   fidx  = (const int*)d_in[3];
  const float* Winit = (const float*)d_in[4];
  const float* binit = (const float*)d_in[5];
  const float* Wf1 = (const float*)d_in[6];
  const float* bf1 = (const float*)d_in[7];
  const float* Wf2 = (const float*)d_in[8];
  const float* bf2 = (const float*)d_in[9];
  const float* Wg1 = (const float*)d_in[10];
  const float* bg1 = (const float*)d_in[11];
  const float* Wg2 = (const float*)d_in[12];
  const float* bg2 = (const float*)d_in[13];
  const float* W1  = (const float*)d_in[14];
  const float* b1  = (const float*)d_in[15];
  const float* gamma = (const float*)d_in[16];
  const float* beta  = (const float*)d_in[17];
  const float* W2  = (const float*)d_in[18];
  const float* b2  = (const float*)d_in[19];

  float* wsf  = (float*)d_ws;
  float* dtb  = wsf;                       // 2 floats (+pad)
  float* zf   = wsf + 16;                  // 256*128
  float* hbuf = zf + BATCH * HID;          // 256*128
  float* p1   = hbuf + BATCH * HID;        // 32*128
  float* p2   = p1 + 32 * HID;             // 32*128
  float* out  = (float*)d_out;

  hipLaunchKernelGGL(k_dt, dim3(1), dim3(256), 0, stream, times, dtb);
  hipLaunchKernelGGL(k_sde, dim3(BATCH), dim3(256), 0, stream, x0, dW, fidx,
                     Winit, binit, Wf1, bf1, Wf2, bf2, Wg1, bg1, Wg2, bg2, dtb,
                     zf);
  hipLaunchKernelGGL(k_ro1, dim3(32), dim3(256), 0, stream, zf, W1, b1, hbuf,
                     p1, p2);
  hipLaunchKernelGGL(k_ro2, dim3(1), dim3(1024), 0, stream, hbuf, p1, p2, gamma,
                     beta, W2, b2, out);
}

// Round 3
// 798.863 us; speedup vs baseline: 1.4603x; 1.4603x over previous
//
#include <hip/hip_runtime.h>
#include <hip/hip_bf16.h>

#define T_STEPS 1000
#define BATCH   256
#define IN_C    32
#define HID     128
#define OUT_C   10

typedef __fp16 h2_t __attribute__((ext_vector_type(2)));

__device__ __forceinline__ float dot2f(uint32_t w, uint32_t a, float acc) {
#if __has_builtin(__builtin_amdgcn_fdot2)
  return __builtin_amdgcn_fdot2(__builtin_bit_cast(h2_t, a),
                                __builtin_bit_cast(h2_t, w), acc, false);
#else
  h2_t av = __builtin_bit_cast(h2_t, a);
  h2_t wv = __builtin_bit_cast(h2_t, w);
  return acc + (float)av[0] * (float)wv[0] + (float)av[1] * (float)wv[1];
#endif
}

__device__ __forceinline__ uint32_t pack_f16(float a, float b) {
#if __has_builtin(__builtin_amdgcn_cvt_pkrtz)
  auto p = __builtin_amdgcn_cvt_pkrtz(a, b);
  return __builtin_bit_cast(uint32_t, p);
#else
  h2_t p; p[0] = (__fp16)a; p[1] = (__fp16)b;
  return __builtin_bit_cast(uint32_t, p);
#endif
}

__device__ __forceinline__ float fast_tanh(float x) {
  float a = x * 2.88539008178f;                 // 2*log2(e)*x
  a = fminf(fmaxf(a, -126.f), 126.f);
#if __has_builtin(__builtin_amdgcn_exp2f)
  float t = __builtin_amdgcn_exp2f(a);
#else
  float t = exp2f(a);
#endif
#if __has_builtin(__builtin_amdgcn_rcpf)
  float r = __builtin_amdgcn_rcpf(t + 1.f);
#else
  float r = 1.f / (t + 1.f);
#endif
  return (t - 1.f) * r;
}

// block-wide barrier WITHOUT draining vmcnt: keeps dW prefetch in flight.
// LDS ordering is guaranteed by lgkmcnt(0); "memory" clobber stops the
// compiler from moving LDS ops across it.
#define WG_BARRIER() asm volatile("s_waitcnt lgkmcnt(0)\n\ts_barrier" ::: "memory")

// ---------------- kernel 0: dt = max(min(diff(times)), 0.001) ----------------
__global__ __launch_bounds__(256) void k_dt(const float* __restrict__ times,
                                            float* __restrict__ dtb) {
  __shared__ float smin[256];
  int tid = threadIdx.x;
  float m = 1e30f;
  for (int t = tid; t < T_STEPS - 1; t += 256)
    m = fminf(m, times[t + 1] - times[t]);
  smin[tid] = m;
  __syncthreads();
  for (int off = 128; off > 0; off >>= 1) {
    if (tid < off) smin[tid] = fminf(smin[tid], smin[tid + off]);
    __syncthreads();
  }
  if (tid == 0) {
    float dt = fmaxf(smin[0], 0.001f);
    dtb[0] = dt;
    dtb[1] = sqrtf(dt);
  }
}

// ---------------- kernel 1: Euler-Maruyama SDE per trajectory ----------------
// block b = trajectory; 512 threads (8 waves -> 2 per SIMD):
//   j = tid>>2 (hidden unit), s = (tid>>1)&1 (f vs g), h = tid&1 (k-half)
// Each thread: half-dot of length 64 as 32 v_dot2; halves combined by shfl_xor(1).
__global__ __launch_bounds__(512) void k_sde(
    const float* __restrict__ x0, const float* __restrict__ dW,
    const int* __restrict__ fidx,
    const float* __restrict__ Winit, const float* __restrict__ binit,
    const float* __restrict__ Wf1, const float* __restrict__ bf1,
    const float* __restrict__ Wf2, const float* __restrict__ bf2,
    const float* __restrict__ Wg1, const float* __restrict__ bg1,
    const float* __restrict__ Wg2, const float* __restrict__ bg2,
    const float* __restrict__ dtb, float* __restrict__ zf) {
  const int b = blockIdx.x;
  const int tid = threadIdx.x;
  const int j = tid >> 2;
  const int s = (tid >> 1) & 1;
  const int h = tid & 1;

  __shared__ alignas(16) uint32_t zp[64];   // z as 64 f16-pairs
  __shared__ alignas(16) uint32_t hfp[64];  // tanh f-hidden
  __shared__ alignas(16) uint32_t hgp[64];  // tanh g-hidden

  const float dt  = dtb[0];
  const float sdt = dtb[1];

  // weight-stationary: this thread's 64-element half-columns as f16 pairs
  const float* M1 = s ? Wg1 : Wf1;
  const float* M2 = s ? Wg2 : Wf2;
  const int r0 = h * 64;
  uint32_t wA[32], wB[32];
#pragma unroll
  for (int k = 0; k < 32; ++k) {
    wA[k] = pack_f16(M1[(r0 + 2 * k) * HID + j], M1[(r0 + 2 * k + 1) * HID + j]);
    wB[k] = pack_f16(M2[(r0 + 2 * k) * HID + j], M2[(r0 + 2 * k + 1) * HID + j]);
  }
  const float bias1 = h ? 0.f : (s ? bg1 : bf1)[j];
  const float bias2 = h ? 0.f : (s ? bg2 : bf2)[j];

  // z0 = x0 @ Winit + binit  (replicated across the 4 (s,h) lanes of j)
  float z = binit[j];
#pragma unroll
  for (int i = 0; i < IN_C; ++i)
    z = fmaf(x0[b * IN_C + i], Winit[i * HID + j], z);

  __fp16* zh = (__fp16*)zp;
  if ((tid & 3) == 0) zh[j] = (__fp16)z;

  const int nsteps = fidx[b];  // in [0, T-1]

  const float* dwp = dW + (size_t)b * HID + j;
  const size_t sBH = (size_t)BATCH * HID;
  float dwA = dwp[0];
  float dwB = dwp[sBH];
  float dwC = dwp[2 * sBH];

  const uint4* zp4 = (const uint4*)zp;
  const uint4* hp4 = (const uint4*)(s ? hgp : hfp);
  __fp16* hdst     = (__fp16*)(s ? hgp : hfp);
  const int c0off  = h * 8;

  WG_BARRIER();

  for (int t = 0; t < nsteps; ++t) {
    float dwv = dwA;
    dwA = dwB;
    dwB = dwC;
    int tn = t + 3;
    if (tn > T_STEPS - 2) tn = T_STEPS - 2;
    dwC = dwp[(size_t)tn * sBH];  // prefetch 3 steps ahead, survives barriers

    // layer 1 half-dot: p = z[h*64 : h*64+64] . W*1[h*64:,j]
    float a0 = bias1, a1 = 0.f, a2 = 0.f, a3 = 0.f;
#pragma unroll
    for (int c = 0; c < 8; ++c) {
      uint4 v = zp4[c0off + c];
      a0 = dot2f(wA[4 * c + 0], v.x, a0);
      a1 = dot2f(wA[4 * c + 1], v.y, a1);
      a2 = dot2f(wA[4 * c + 2], v.z, a2);
      a3 = dot2f(wA[4 * c + 3], v.w, a3);
    }
    float p = (a0 + a1) + (a2 + a3);
    p += __shfl_xor(p, 1, 64);          // combine k-halves
    float h1 = fast_tanh(p);
    if (h == 0) hdst[j] = (__fp16)h1;
    WG_BARRIER();

    // layer 2 half-dot
    float q0 = bias2, q1 = 0.f, q2 = 0.f, q3 = 0.f;
#pragma unroll
    for (int c = 0; c < 8; ++c) {
      uint4 v = hp4[c0off + c];
      q0 = dot2f(wB[4 * c + 0], v.x, q0);
      q1 = dot2f(wB[4 * c + 1], v.y, q1);
      q2 = dot2f(wB[4 * c + 2], v.z, q2);
      q3 = dot2f(wB[4 * c + 3], v.w, q3);
    }
    float q = (q0 + q1) + (q2 + q3);
    q += __shfl_xor(q, 1, 64);          // combine k-halves
    float tg  = fast_tanh(q);           // meaningful for s=1 (g tanh-bounded)
    float val = s ? tg : q;
    float oth = __shfl_xor(val, 2, 64); // exchange f <-> g
    float fv = s ? oth : val;
    float gv = s ? val : oth;
    z = fmaf(fv, dt, fmaf(gv, sdt * dwv, z));
    if ((tid & 3) == 0) zh[j] = (__fp16)z;
    WG_BARRIER();
  }

  if ((tid & 3) == 0) zf[b * HID + j] = z;
}

// ---------------- kernel 2a: h = zf @ W1 + b1, per-block column partial stats --
__global__ __launch_bounds__(256) void k_ro1(const float* __restrict__ zf,
                                             const float* __restrict__ W1,
                                             const float* __restrict__ b1,
                                             float* __restrict__ hbuf,
                                             float* __restrict__ p1,
                                             float* __restrict__ p2) {
  int blk = blockIdx.x;  // 32 blocks x 8 rows
  int tid = threadIdx.x;
  int j = tid & 127, half = tid >> 7;
  int b0 = blk * 8 + half * 4;
  float acc[4];
  float bj = b1[j];
#pragma unroll
  for (int r = 0; r < 4; ++r) acc[r] = bj;
  for (int i = 0; i < HID; ++i) {
    float w = W1[i * HID + j];
#pragma unroll
    for (int r = 0; r < 4; ++r)
      acc[r] = fmaf(zf[(b0 + r) * HID + i], w, acc[r]);
  }
  float s1 = 0.f, s2 = 0.f;
#pragma unroll
  for (int r = 0; r < 4; ++r) {
    hbuf[(b0 + r) * HID + j] = acc[r];
    s1 += acc[r];
    s2 = fmaf(acc[r], acc[r], s2);
  }
  __shared__ float q1[2][128], q2[2][128];
  q1[half][j] = s1;
  q2[half][j] = s2;
  __syncthreads();
  if (tid < 128) {
    p1[blk * HID + tid] = q1[0][tid] + q1[1][tid];
    p2[blk * HID + tid] = q2[0][tid] + q2[1][tid];
  }
}

// ---------------- kernel 2b: BN + ReLU + W2 readout ---------------------------
__global__ __launch_bounds__(1024) void k_ro2(
    const float* __restrict__ hbuf, const float* __restrict__ p1,
    const float* __restrict__ p2, const float* __restrict__ gamma,
    const float* __restrict__ beta, const float* __restrict__ W2,
    const float* __restrict__ b2, float* __restrict__ out) {
  __shared__ float sa[128], sc[128];
  int tid = threadIdx.x;
  if (tid < 128) {
    float m = 0.f, q = 0.f;
    for (int blk = 0; blk < 32; ++blk) {
      m += p1[blk * HID + tid];
      q += p2[blk * HID + tid];
    }
    m *= (1.f / BATCH);
    q *= (1.f / BATCH);
    float var = q - m * m;
    float r = rsqrtf(var + 1e-5f);
    float a = gamma[tid] * r;
    sa[tid] = a;
    sc[tid] = beta[tid] - m * a;
  }
  __syncthreads();
  for (int idx = tid; idx < BATCH * OUT_C; idx += 1024) {
    int b = idx / OUT_C;
    int o = idx - b * OUT_C;
    float acc = b2[o];
    for (int jj = 0; jj < HID; ++jj) {
      float hn = fmaxf(fmaf(sa[jj], hbuf[b * HID + jj], sc[jj]), 0.f);
      acc = fmaf(hn, W2[jj * OUT_C + o], acc);
    }
    out[idx] = acc;
  }
}

extern "C" void kernel_launch(void* const* d_in, const int* in_sizes, int n_in,
                              void* d_out, int out_size, void* d_ws, size_t ws_size,
                              hipStream_t stream) {
  const float* times = (const float*)d_in[0];
  const float* x0    = (const float*)d_in[1];
  const float* dW    = (const float*)d_in[2];
  const int*   fidx  = (const int*)d_in[3];
  const float* Winit = (const float*)d_in[4];
  const float* binit = (const float*)d_in[5];
  const float* Wf1 = (const float*)d_in[6];
  const float* bf1 = (const float*)d_in[7];
  const float* Wf2 = (const float*)d_in[8];
  const float* bf2 = (const float*)d_in[9];
  const float* Wg1 = (const float*)d_in[10];
  const float* bg1 = (const float*)d_in[11];
  const float* Wg2 = (const float*)d_in[12];
  const float* bg2 = (const float*)d_in[13];
  const float* W1  = (const float*)d_in[14];
  const float* b1  = (const float*)d_in[15];
  const float* gamma = (const float*)d_in[16];
  const float* beta  = (const float*)d_in[17];
  const float* W2  = (const float*)d_in[18];
  const float* b2  = (const float*)d_in[19];

  float* wsf  = (float*)d_ws;
  float* dtb  = wsf;                       // 2 floats (+pad)
  float* zf   = wsf + 16;                  // 256*128
  float* hbuf = zf + BATCH * HID;          // 256*128
  float* p1   = hbuf + BATCH * HID;        // 32*128
  float* p2   = p1 + 32 * HID;             // 32*128
  float* out  = (float*)d_out;

  hipLaunchKernelGGL(k_dt, dim3(1), dim3(256), 0, stream, times, dtb);
  hipLaunchKernelGGL(k_sde, dim3(BATCH), dim3(512), 0, stream, x0, dW, fidx,
                     Winit, binit, Wf1, bf1, Wf2, bf2, Wg1, bg1, Wg2, bg2, dtb,
                     zf);
  hipLaunchKernelGGL(k_ro1, dim3(32), dim3(256), 0, stream, zf, W1, b1, hbuf,
                     p1, p2);
  hipLaunchKernelGGL(k_ro2, dim3(1), dim3(1024), 0, stream, hbuf, p1, p2, gamma,
                     beta, W2, b2, out);
}

// Round 4
// 712.690 us; speedup vs baseline: 1.6369x; 1.1209x over previous
//
#include <hip/hip_runtime.h>
#include <hip/hip_bf16.h>

#define T_STEPS 1000
#define BATCH   256
#define IN_C    32
#define HID     128
#define OUT_C   10

typedef __fp16 h2_t __attribute__((ext_vector_type(2)));

__device__ __forceinline__ float dot2f(uint32_t w, uint32_t a, float acc) {
#if __has_builtin(__builtin_amdgcn_fdot2)
  return __builtin_amdgcn_fdot2(__builtin_bit_cast(h2_t, a),
                                __builtin_bit_cast(h2_t, w), acc, false);
#else
  h2_t av = __builtin_bit_cast(h2_t, a);
  h2_t wv = __builtin_bit_cast(h2_t, w);
  return acc + (float)av[0] * (float)wv[0] + (float)av[1] * (float)wv[1];
#endif
}

__device__ __forceinline__ uint32_t pack_f16(float a, float b) {
#if __has_builtin(__builtin_amdgcn_cvt_pkrtz)
  auto p = __builtin_amdgcn_cvt_pkrtz(a, b);
  return __builtin_bit_cast(uint32_t, p);
#else
  h2_t p; p[0] = (__fp16)a; p[1] = (__fp16)b;
  return __builtin_bit_cast(uint32_t, p);
#endif
}

// quad_perm DPP lane swaps (VALU-speed, replaces ds_swizzle-based __shfl_xor)
__device__ __forceinline__ float dpp_xor1(float x) {   // lane ^= 1 within quad
  return __builtin_bit_cast(float, __builtin_amdgcn_update_dpp(
      0, __builtin_bit_cast(int, x), 0xB1, 0xF, 0xF, true));
}
__device__ __forceinline__ float dpp_xor2(float x) {   // lane ^= 2 within quad
  return __builtin_bit_cast(float, __builtin_amdgcn_update_dpp(
      0, __builtin_bit_cast(int, x), 0x4E, 0xF, 0xF, true));
}

__device__ __forceinline__ float fast_tanh(float x) {
  float a = x * 2.88539008178f;                 // 2*log2(e)*x
  a = fminf(fmaxf(a, -126.f), 126.f);
#if __has_builtin(__builtin_amdgcn_exp2f)
  float t = __builtin_amdgcn_exp2f(a);
#else
  float t = exp2f(a);
#endif
#if __has_builtin(__builtin_amdgcn_rcpf)
  float r = __builtin_amdgcn_rcpf(t + 1.f);
#else
  float r = 1.f / (t + 1.f);
#endif
  return (t - 1.f) * r;
}

// block barrier WITHOUT draining vmcnt: dW prefetch stays in flight.
#define WG_BARRIER() asm volatile("s_waitcnt lgkmcnt(0)\n\ts_barrier" ::: "memory")

// ---------------- kernel 0: dt = max(min(diff(times)), 0.001) ----------------
__global__ __launch_bounds__(256) void k_dt(const float* __restrict__ times,
                                            float* __restrict__ dtb) {
  __shared__ float smin[256];
  int tid = threadIdx.x;
  float m = 1e30f;
  for (int t = tid; t < T_STEPS - 1; t += 256)
    m = fminf(m, times[t + 1] - times[t]);
  smin[tid] = m;
  __syncthreads();
  for (int off = 128; off > 0; off >>= 1) {
    if (tid < off) smin[tid] = fminf(smin[tid], smin[tid + off]);
    __syncthreads();
  }
  if (tid == 0) {
    float dt = fmaxf(smin[0], 0.001f);
    dtb[0] = dt;
    dtb[1] = sqrtf(dt);
  }
}

// ---------------- kernel 1: Euler-Maruyama SDE per trajectory ----------------
// block b = trajectory; 512 threads: quad = (h=bit0: k-half, s=bit1: f/g), j = tid>>2.
// Thread (j,s,h) computes a 64-long half-dot; k-assignment interleaved in 8-elem
// chunks (thread h owns k in [16c+8h, 16c+8h+8)) so the two h-groups of a wave
// read bank-disjoint LDS chunks. hf/hg packed with 288B stride => (s,h) groups
// hit bank offsets {0,4,8,12}: conflict-free broadcast reads.
__global__ __launch_bounds__(512) void k_sde(
    const float* __restrict__ x0, const float* __restrict__ dW,
    const int* __restrict__ fidx,
    const float* __restrict__ Winit, const float* __restrict__ binit,
    const float* __restrict__ Wf1, const float* __restrict__ bf1,
    const float* __restrict__ Wf2, const float* __restrict__ bf2,
    const float* __restrict__ Wg1, const float* __restrict__ bg1,
    const float* __restrict__ Wg2, const float* __restrict__ bg2,
    const float* __restrict__ dtb, float* __restrict__ zf) {
  const int b = blockIdx.x;
  const int tid = threadIdx.x;
  const int j = tid >> 2;
  const int s = (tid >> 1) & 1;
  const int h = tid & 1;

  __shared__ alignas(16) uint4 zp4[16];   // z as 128 f16 (16 chunks of 8)
  __shared__ alignas(16) uint4 hb[36];    // hf = hb[0..16), hg = hb[18..34)

  const float dt  = dtb[0];
  const float sdt = dtb[1];

  // weight-stationary packing, matching the interleaved chunk order:
  // read c pulls chunk m=2c+h holding elements 8m..8m+7 (pairs 4m..4m+3)
  const float* M1 = s ? Wg1 : Wf1;
  const float* M2 = s ? Wg2 : Wf2;
  uint32_t wA[32], wB[32];
#pragma unroll
  for (int c = 0; c < 8; ++c) {
    int k0 = (2 * c + h) * 8;
#pragma unroll
    for (int d = 0; d < 4; ++d) {
      wA[4 * c + d] = pack_f16(M1[(k0 + 2 * d) * HID + j], M1[(k0 + 2 * d + 1) * HID + j]);
      wB[4 * c + d] = pack_f16(M2[(k0 + 2 * d) * HID + j], M2[(k0 + 2 * d + 1) * HID + j]);
    }
  }
  const float bias1 = h ? 0.f : (s ? bg1 : bf1)[j];
  const float bias2 = h ? 0.f : (s ? bg2 : bf2)[j];

  // z0 = x0 @ Winit + binit  (replicated across the 4 (s,h) lanes of j)
  float z = binit[j];
#pragma unroll
  for (int i = 0; i < IN_C; ++i)
    z = fmaf(x0[b * IN_C + i], Winit[i * HID + j], z);

  __fp16* zh = (__fp16*)zp4;
  if ((tid & 3) == 0) zh[j] = (__fp16)z;

  const int nsteps = fidx[b];  // in [0, T-1]

  const float* dwp = dW + (size_t)b * HID + j;
  const size_t sBH = (size_t)BATCH * HID;
  float dwA = dwp[0];
  float dwB = dwp[sBH];
  float dwC = dwp[2 * sBH];

  const uint4* hp4 = hb + s * 18;
  __fp16* hdst     = (__fp16*)(hb + s * 18);

  WG_BARRIER();

  for (int t = 0; t < nsteps; ++t) {
    float dwv = dwA;
    dwA = dwB;
    dwB = dwC;
    int tn = t + 3;
    if (tn > T_STEPS - 2) tn = T_STEPS - 2;
    dwC = dwp[(size_t)tn * sBH];  // prefetch 3 steps ahead, survives barriers

    // layer 1 half-dot over this thread's interleaved k-chunks
    float a0 = bias1, a1 = 0.f, a2 = 0.f, a3 = 0.f;
#pragma unroll
    for (int c = 0; c < 8; ++c) {
      uint4 v = zp4[2 * c + h];
      a0 = dot2f(wA[4 * c + 0], v.x, a0);
      a1 = dot2f(wA[4 * c + 1], v.y, a1);
      a2 = dot2f(wA[4 * c + 2], v.z, a2);
      a3 = dot2f(wA[4 * c + 3], v.w, a3);
    }
    float p = (a0 + a1) + (a2 + a3);
    p += dpp_xor1(p);                   // combine k-halves (VALU DPP)
    float h1 = fast_tanh(p);
    if (h == 0) hdst[j] = (__fp16)h1;
    WG_BARRIER();

    // layer 2 half-dot
    float q0 = bias2, q1 = 0.f, q2 = 0.f, q3 = 0.f;
#pragma unroll
    for (int c = 0; c < 8; ++c) {
      uint4 v = hp4[2 * c + h];
      q0 = dot2f(wB[4 * c + 0], v.x, q0);
      q1 = dot2f(wB[4 * c + 1], v.y, q1);
      q2 = dot2f(wB[4 * c + 2], v.z, q2);
      q3 = dot2f(wB[4 * c + 3], v.w, q3);
    }
    float q = (q0 + q1) + (q2 + q3);
    q += dpp_xor1(q);                   // combine k-halves
    float tg  = fast_tanh(q);           // meaningful for s=1 (g tanh-bounded)
    float val = s ? tg : q;
    float oth = dpp_xor2(val);          // exchange f <-> g
    float fv = s ? oth : val;
    float gv = s ? val : oth;
    z = fmaf(fv, dt, fmaf(gv, sdt * dwv, z));
    if ((tid & 3) == 0) zh[j] = (__fp16)z;
    WG_BARRIER();
  }

  if ((tid & 3) == 0) zf[b * HID + j] = z;
}

// ---------------- kernel 2a: h = zf @ W1 + b1, per-block column partial stats --
__global__ __launch_bounds__(256) void k_ro1(const float* __restrict__ zf,
                                             const float* __restrict__ W1,
                                             const float* __restrict__ b1,
                                             float* __restrict__ hbuf,
                                             float* __restrict__ p1,
                                             float* __restrict__ p2) {
  int blk = blockIdx.x;  // 32 blocks x 8 rows
  int tid = threadIdx.x;
  int j = tid & 127, half = tid >> 7;
  int b0 = blk * 8 + half * 4;
  float acc[4];
  float bj = b1[j];
#pragma unroll
  for (int r = 0; r < 4; ++r) acc[r] = bj;
  for (int i = 0; i < HID; ++i) {
    float w = W1[i * HID + j];
#pragma unroll
    for (int r = 0; r < 4; ++r)
      acc[r] = fmaf(zf[(b0 + r) * HID + i], w, acc[r]);
  }
  float s1 = 0.f, s2 = 0.f;
#pragma unroll
  for (int r = 0; r < 4; ++r) {
    hbuf[(b0 + r) * HID + j] = acc[r];
    s1 += acc[r];
    s2 = fmaf(acc[r], acc[r], s2);
  }
  __shared__ float q1[2][128], q2[2][128];
  q1[half][j] = s1;
  q2[half][j] = s2;
  __syncthreads();
  if (tid < 128) {
    p1[blk * HID + tid] = q1[0][tid] + q1[1][tid];
    p2[blk * HID + tid] = q2[0][tid] + q2[1][tid];
  }
}

// ---------------- kernel 2b: BN + ReLU + W2 readout ---------------------------
__global__ __launch_bounds__(1024) void k_ro2(
    const float* __restrict__ hbuf, const float* __restrict__ p1,
    const float* __restrict__ p2, const float* __restrict__ gamma,
    const float* __restrict__ beta, const float* __restrict__ W2,
    const float* __restrict__ b2, float* __restrict__ out) {
  __shared__ float sa[128], sc[128];
  int tid = threadIdx.x;
  if (tid < 128) {
    float m = 0.f, q = 0.f;
    for (int blk = 0; blk < 32; ++blk) {
      m += p1[blk * HID + tid];
      q += p2[blk * HID + tid];
    }
    m *= (1.f / BATCH);
    q *= (1.f / BATCH);
    float var = q - m * m;
    float r = rsqrtf(var + 1e-5f);
    float a = gamma[tid] * r;
    sa[tid] = a;
    sc[tid] = beta[tid] - m * a;
  }
  __syncthreads();
  for (int idx = tid; idx < BATCH * OUT_C; idx += 1024) {
    int b = idx / OUT_C;
    int o = idx - b * OUT_C;
    float acc = b2[o];
    for (int jj = 0; jj < HID; ++jj) {
      float hn = fmaxf(fmaf(sa[jj], hbuf[b * HID + jj], sc[jj]), 0.f);
      acc = fmaf(hn, W2[jj * OUT_C + o], acc);
    }
    out[idx] = acc;
  }
}

extern "C" void kernel_launch(void* const* d_in, const int* in_sizes, int n_in,
                              void* d_out, int out_size, void* d_ws, size_t ws_size,
                              hipStream_t stream) {
  const float* times = (const float*)d_in[0];
  const float* x0    = (const float*)d_in[1];
  const float* dW    = (const float*)d_in[2];
  const int*   fidx  = (const int*)d_in[3];
  const float* Winit = (const float*)d_in[4];
  const float* binit = (const float*)d_in[5];
  const float* Wf1 = (const float*)d_in[6];
  const float* bf1 = (const float*)d_in[7];
  const float* Wf2 = (const float*)d_in[8];
  const float* bf2 = (const float*)d_in[9];
  const float* Wg1 = (const float*)d_in[10];
  const float* bg1 = (const float*)d_in[11];
  const float* Wg2 = (const float*)d_in[12];
  const float* bg2 = (const float*)d_in[13];
  const float* W1  = (const float*)d_in[14];
  const float* b1  = (const float*)d_in[15];
  const float* gamma = (const float*)d_in[16];
  const float* beta  = (const float*)d_in[17];
  const float* W2  = (const float*)d_in[18];
  const float* b2  = (const float*)d_in[19];

  float* wsf  = (float*)d_ws;
  float* dtb  = wsf;                       // 2 floats (+pad)
  float* zf   = wsf + 16;                  // 256*128
  float* hbuf = zf + BATCH * HID;          // 256*128
  float* p1   = hbuf + BATCH * HID;        // 32*128
  float* p2   = p1 + 32 * HID;             // 32*128
  float* out  = (float*)d_out;

  hipLaunchKernelGGL(k_dt, dim3(1), dim3(256), 0, stream, times, dtb);
  hipLaunchKernelGGL(k_sde, dim3(BATCH), dim3(512), 0, stream, x0, dW, fidx,
                     Winit, binit, Wf1, bf1, Wf2, bf2, Wg1, bg1, Wg2, bg2, dtb,
                     zf);
  hipLaunchKernelGGL(k_ro1, dim3(32), dim3(256), 0, stream, zf, W1, b1, hbuf,
                     p1, p2);
  hipLaunchKernelGGL(k_ro2, dim3(1), dim3(1024), 0, stream, hbuf, p1, p2, gamma,
                     beta, W2, b2, out);
}